// Round 6
// baseline (3070.620 us; speedup 1.0000x reference)
//
#include <hip/hip_runtime.h>
#include <hip/hip_bf16.h>

#define TT 16000
#define BB 4
#define NLAYER 16
#define USTR 232    // klayer stage-1 B-operand row stride (shorts): 224 + 8 pad
#define U2STR 72    // acts row stride (shorts): 64 + 8 pad
#define M3STR 264   // kfinal mid row stride (shorts): 256 + 8 pad

#define A1SZ (NLAYER*8*7*512)   // gate-weight A-frags
#define A2SZ (NLAYER*4*2*512)   // res-weight A-frags
#define SWSZ (16*32*512)        // skip-weight A-frags (M=256, K=1024)
#define OWSZ (16*8*512)         // out/end-weight A-frags (M=256, K=256)
#define AUPSZ (20*10*512)       // upsample A-frags (M=320, K=320)
#define BUPSZ (1000*10*512)     // upsample B-frags (K=320, N=16000)

typedef unsigned short ushort_t;
typedef short v8s __attribute__((ext_vector_type(8)));
typedef short v4s __attribute__((ext_vector_type(4)));
typedef float v4f __attribute__((ext_vector_type(4)));

#define MFMA16 __builtin_amdgcn_mfma_f32_16x16x32_bf16

__device__ __forceinline__ float bf2f(ushort_t u) {
  unsigned int x = ((unsigned int)u) << 16;
  float f; __builtin_memcpy(&f, &x, 4); return f;
}
__device__ __forceinline__ ushort_t f2bf(float f) {
  unsigned int x; __builtin_memcpy(&x, &f, 4);
  x += 0x7fffu + ((x >> 16) & 1u);   // RNE
  return (ushort_t)(x >> 16);
}

// ---------------------------------------------------------------------------
// Prep: pack every weight matrix into exact MFMA fragment order (bf16).
// A-frag: elem j of lane l = A[m = mt*16 + (l&15)][k = ks*32 + (l>>4)*8 + j]
// B-frag: elem j of lane l = B[k = ks*32 + (l>>4)*8 + j][n = nt*16 + (l&15)]
// Also: embed gather -> x0, upsample operands Aup/Bup.
// ---------------------------------------------------------------------------
__global__ __launch_bounds__(256) void kprep(
    const float* __restrict__ feat, const int* __restrict__ fin,
    const float* __restrict__ embed, const float* __restrict__ up_w,
    const float* __restrict__ cond_w, const float* __restrict__ cond_b,
    const float* __restrict__ dil_w, const float* __restrict__ dil_b,
    const float* __restrict__ res_w, const float* __restrict__ skip_w,
    const float* __restrict__ skip_b, const float* __restrict__ out_w,
    const float* __restrict__ end_w,
    ushort_t* __restrict__ A1, ushort_t* __restrict__ A2,
    ushort_t* __restrict__ SWf, ushort_t* __restrict__ OWf,
    ushort_t* __restrict__ EWf, ushort_t* __restrict__ Aup,
    ushort_t* __restrict__ Bup, ushort_t* __restrict__ x0,
    float* __restrict__ Bcomb, float* __restrict__ SBsum) {
  int tid = blockIdx.x * 256 + threadIdx.x;
  int np = gridDim.x * 256;
  // A1: gate GEMM [16 layers][8 Mtiles][7 Ksteps][64 lanes][8]
  // K rows: 0..63 = xc (tap1), 64..127 = xp (tap0), 128..207 = cond, pad=0
  for (int idx = tid; idx < A1SZ; idx += np) {
    int j = idx & 7, lane = (idx >> 3) & 63;
    int r_ = idx >> 9;
    int ks = r_ % 7; int r2 = r_ / 7;
    int mt = r2 & 7; int i = r2 >> 3;
    int m = mt * 16 + (lane & 15);
    int k = ks * 32 + (lane >> 4) * 8 + j;
    float v = 0.f;
    if (k < 64)       v = dil_w[((i * 128 + m) * 64 + k) * 2 + 1];
    else if (k < 128) v = dil_w[((i * 128 + m) * 64 + (k - 64)) * 2 + 0];
    else if (k < 208) v = cond_w[(i * 128 + m) * 80 + (k - 128)];
    A1[idx] = f2bf(v);
  }
  // A2: res GEMM [16][4 Mtiles][2 Ksteps][64][8] (layer 15 zeroed/unused)
  for (int idx = tid; idx < A2SZ; idx += np) {
    int j = idx & 7, lane = (idx >> 3) & 63;
    int r_ = idx >> 9;
    int ks = r_ & 1; int mt = (r_ >> 1) & 3; int i = r_ >> 3;
    int m = mt * 16 + (lane & 15);
    int k = ks * 32 + (lane >> 4) * 8 + j;
    A2[idx] = f2bf(i < 15 ? res_w[(i * 64 + m) * 64 + k] : 0.f);
  }
  // SWf: skip GEMM [16 Mtiles][32 Ksteps][64][8], K = layer*64 + ch
  for (int idx = tid; idx < SWSZ; idx += np) {
    int j = idx & 7, lane = (idx >> 3) & 63;
    int r_ = idx >> 9;
    int ks = r_ & 31; int mt = r_ >> 5;
    int m = mt * 16 + (lane & 15);
    int k = ks * 32 + (lane >> 4) * 8 + j;
    int i = k >> 6, ch = k & 63;
    SWf[idx] = f2bf(skip_w[(i * 256 + m) * 64 + ch]);
  }
  // OWf/EWf: [16 Mtiles][8 Ksteps][64][8]
  for (int idx = tid; idx < OWSZ; idx += np) {
    int j = idx & 7, lane = (idx >> 3) & 63;
    int r_ = idx >> 9;
    int ks = r_ & 7; int mt = r_ >> 3;
    int m = mt * 16 + (lane & 15);
    int k = ks * 32 + (lane >> 4) * 8 + j;
    OWf[idx] = f2bf(out_w[m * 256 + k]);
    EWf[idx] = f2bf(end_w[m * 256 + k]);
  }
  // Aup: [20 Mtiles][10 Ks][64][8]; A[mrow=(b*80+q)][km=(m*80+i)] =
  //   feat[b,i,q-m] (0 if q<m)
  for (int idx = tid; idx < AUPSZ; idx += np) {
    int j = idx & 7, lane = (idx >> 3) & 63;
    int r_ = idx >> 9;
    int ks = r_ % 10; int mt = r_ / 10;
    int mrow = mt * 16 + (lane & 15);
    int km = ks * 32 + (lane >> 4) * 8 + j;
    int b = mrow / 80, q = mrow % 80;
    int m = km / 80, i = km % 80;
    int jj = q - m;
    Aup[idx] = f2bf(jj >= 0 ? feat[(b * 80 + i) * 80 + jj] : 0.f);
  }
  // Bup: [1000 Ntiles][10 Ks][64][8]; B[km][col=(o*200+r)] =
  //   up_w[i, o, 200m + r]
  for (int idx = tid; idx < BUPSZ; idx += np) {
    int j = idx & 7, lane = (idx >> 3) & 63;
    int r_ = idx >> 9;
    int ks = r_ % 10; int nt = r_ / 10;
    int km = ks * 32 + (lane >> 4) * 8 + j;
    int m = km / 80, i = km % 80;
    int col = nt * 16 + (lane & 15);
    int o = col / 200, r = col % 200;
    Bup[idx] = f2bf(up_w[(size_t)(i * 80 + o) * 800 + m * 200 + r]);
  }
  // embed gather: x0[b][t][ch] bf16
  for (int idx = tid; idx < BB * TT * 64; idx += np) {
    int k = idx & 63;
    int bt = idx >> 6;            // b*TT + t
    x0[idx] = f2bf(embed[fin[bt] * 64 + k]);
  }
  for (int idx = tid; idx < NLAYER * 128; idx += np)
    Bcomb[idx] = dil_b[idx] + cond_b[idx];
  for (int idx = tid; idx < 256; idx += np) {
    float s = 0.f;
    for (int i = 0; i < NLAYER; i++) s += skip_b[i * 256 + idx];
    SBsum[idx] = s;
  }
}

// ---------------------------------------------------------------------------
// Upsample GEMM, MFMA: M=320 (b,q), K=320 (m,i), N=16000 (o*200+r).
// Pure register GEMM (no LDS): block = 4 N-tiles (64 cols), wave w owns
// M-tiles w*5..w*5+4. Output cond[b][t][80] bf16, t = q*200+r.
// ---------------------------------------------------------------------------
__global__ __launch_bounds__(256) void kup(
    const ushort_t* __restrict__ Aup, const ushort_t* __restrict__ Bup,
    const float* __restrict__ up_b, ushort_t* __restrict__ cond) {
  int nt0 = blockIdx.x * 4;
  int lane = threadIdx.x & 63;
  int w = threadIdx.x >> 6;
  int tl = lane & 15, quad = lane >> 4;
  v4f acc[5][4];
  #pragma unroll
  for (int mt = 0; mt < 5; mt++)
    #pragma unroll
    for (int nt = 0; nt < 4; nt++) acc[mt][nt] = 0.f;
  #pragma unroll
  for (int ks = 0; ks < 10; ks++) {
    v8s bf[4];
    #pragma unroll
    for (int nt = 0; nt < 4; nt++)
      bf[nt] = *(const v8s*)(Bup + (((size_t)(nt0 + nt) * 10 + ks) * 64 + lane) * 8);
    #pragma unroll
    for (int mt = 0; mt < 5; mt++) {
      v8s a = *(const v8s*)(Aup + (((size_t)(w * 5 + mt) * 10 + ks) * 64 + lane) * 8);
      #pragma unroll
      for (int nt = 0; nt < 4; nt++)
        acc[mt][nt] = MFMA16(a, bf[nt], acc[mt][nt], 0, 0, 0);
    }
  }
  #pragma unroll
  for (int mt = 0; mt < 5; mt++) {
    #pragma unroll
    for (int nt = 0; nt < 4; nt++) {
      int col = (nt0 + nt) * 16 + tl;
      int o = col / 200, r = col % 200;
      float bias = up_b[o];
      #pragma unroll
      for (int rg = 0; rg < 4; rg++) {
        int mrow = (w * 5 + mt) * 16 + quad * 4 + rg;
        int b = mrow / 80, q = mrow % 80;
        cond[((size_t)b * TT + q * 200 + r) * 80 + o] = f2bf(acc[mt][nt][rg] + bias);
      }
    }
  }
}

// ---------------------------------------------------------------------------
// One WaveNet layer, MFMA. Block = (64 t) x (one b). 4 waves.
// Stage 1: gate GEMM M=128, K=224 (xc|xp|cond|pad), N=64. Wave w owns
// M-tiles {w, w+4} so channel p and p+64 land in the same lane/reg ->
// lane-local tanh*sigmoid. Acts -> LDS U2 (B-layout) + global (bf16,
// deferred skip). Stage 2: res GEMM M=64 K=64 + residual -> x ping-pong.
// ---------------------------------------------------------------------------
__global__ __launch_bounds__(256) void klayer(
    const ushort_t* __restrict__ xin, ushort_t* __restrict__ xout,
    const ushort_t* __restrict__ cond, ushort_t* __restrict__ actsl,
    const ushort_t* __restrict__ A1l, const ushort_t* __restrict__ A2l,
    const float* __restrict__ Bb, const float* __restrict__ rbias,
    int d, int last) {
  __shared__ ushort_t U[64 * USTR];    // 29.0 KB: B-operand [t][k]
  __shared__ ushort_t U2[64 * U2STR];  //  9.0 KB: acts [t][ch]
  int b = blockIdx.y;
  int t0 = blockIdx.x * 64;
  int tidx = threadIdx.x;
  int lane = tidx & 63;
  int w = tidx >> 6;
  int tl = lane & 15, quad = lane >> 4;

  // ---- stage B-operand: U[t][0..63]=xc, [64..127]=xp, [128..207]=cond ----
  const ushort_t* xb = xin + ((size_t)b * TT + t0) * 64;
  for (int e = tidx * 8; e < 4096; e += 2048) {
    int t = e >> 6, c = e & 63;
    *(v8s*)&U[t * USTR + c] = *(const v8s*)(xb + e);
  }
  for (int e = tidx * 8; e < 4096; e += 2048) {
    int t = e >> 6, c = e & 63;
    int tp = t0 + t - d;
    v8s v = 0;
    if (tp >= 0) v = *(const v8s*)(xin + ((size_t)b * TT + tp) * 64 + c);
    *(v8s*)&U[t * USTR + 64 + c] = v;
  }
  const ushort_t* cbp = cond + ((size_t)b * TT + t0) * 80;
  for (int e = tidx * 8; e < 5120; e += 2048) {
    int t = e / 80, c = e - t * 80;
    *(v8s*)&U[t * USTR + 128 + c] = *(const v8s*)(cbp + e);
  }
  {  // zero K-pad 208..223 (must be finite: mfma multiplies it)
    int e = tidx * 4;
    int t = e >> 4, c = e & 15;
    *(v4s*)&U[t * USTR + 208 + c] = (v4s)0;
  }
  __syncthreads();

  // ---- stage 1: gate GEMM ----
  v4f acc0[4], acc1[4];
  #pragma unroll
  for (int nt = 0; nt < 4; nt++) { acc0[nt] = 0.f; acc1[nt] = 0.f; }
  #pragma unroll
  for (int ks = 0; ks < 7; ks++) {
    v8s a0 = *(const v8s*)(A1l + (((size_t)w * 7 + ks) * 64 + lane) * 8);
    v8s a1 = *(const v8s*)(A1l + (((size_t)(w + 4) * 7 + ks) * 64 + lane) * 8);
    #pragma unroll
    for (int nt = 0; nt < 4; nt++) {
      v8s bf = *(const v8s*)&U[(nt * 16 + tl) * USTR + ks * 32 + quad * 8];
      acc0[nt] = MFMA16(a0, bf, acc0[nt], 0, 0, 0);
      acc1[nt] = MFMA16(a1, bf, acc1[nt], 0, 0, 0);
    }
  }

  // ---- gates: ch = w*16 + quad*4 + r (pair ch, ch+64 lane-local) ----
  int cha = w * 16 + quad * 4;
  float ba[4], bb_[4];
  #pragma unroll
  for (int r = 0; r < 4; r++) { ba[r] = Bb[cha + r]; bb_[r] = Bb[64 + cha + r]; }
  #pragma unroll
  for (int nt = 0; nt < 4; nt++) {
    int t = nt * 16 + tl;
    #pragma unroll
    for (int r = 0; r < 4; r++) {
      float ia = acc0[nt][r] + ba[r];
      float ib = acc1[nt][r] + bb_[r];
      float ax = fabsf(ia);
      float e2 = __expf(-2.f * ax);
      float th = __builtin_copysignf((1.f - e2) / (1.f + e2), ia);
      float sg = 1.f / (1.f + __expf(-ib));
      U2[t * U2STR + cha + r] = f2bf(th * sg);
    }
  }
  __syncthreads();

  // ---- acts -> global (vectorized, deferred skip GEMM reads these) ----
  ushort_t* ab = actsl + ((size_t)b * TT + t0) * 64;
  for (int e = tidx * 8; e < 4096; e += 2048) {
    int t = e >> 6, c = e & 63;
    *(v8s*)(ab + e) = *(const v8s*)&U2[t * U2STR + c];
  }

  // ---- stage 2: res GEMM + residual (dead code at layer 15) ----
  if (!last) {
    v4f acc2[4];
    #pragma unroll
    for (int nt = 0; nt < 4; nt++) {
      v4f z;
      #pragma unroll
      for (int r = 0; r < 4; r++) z[r] = rbias[cha + r];
      acc2[nt] = z;
    }
    #pragma unroll
    for (int ks = 0; ks < 2; ks++) {
      v8s a = *(const v8s*)(A2l + (((size_t)w * 2 + ks) * 64 + lane) * 8);
      #pragma unroll
      for (int nt = 0; nt < 4; nt++) {
        v8s bf = *(const v8s*)&U2[(nt * 16 + tl) * U2STR + ks * 32 + quad * 8];
        acc2[nt] = MFMA16(a, bf, acc2[nt], 0, 0, 0);
      }
    }
    // residual add (xc from U k<64), park in U xp-region for vector store
    #pragma unroll
    for (int nt = 0; nt < 4; nt++) {
      int t = nt * 16 + tl;
      #pragma unroll
      for (int r = 0; r < 4; r++) {
        float xcv = bf2f(U[t * USTR + cha + r]);
        U[t * USTR + 64 + cha + r] = f2bf(acc2[nt][r] + xcv);
      }
    }
    __syncthreads();
    ushort_t* xob = xout + ((size_t)b * TT + t0) * 64;
    for (int e = tidx * 8; e < 4096; e += 2048) {
      int t = e >> 6, c = e & 63;
      *(v8s*)(xob + e) = *(const v8s*)&U[t * USTR + 64 + c];
    }
  }
}

// ---------------------------------------------------------------------------
// Final fused MFMA chain: skip GEMM (M=256, K=1024) with software-pipelined
// acts fragment loads (register double-buffer, prefetch ksg+1 during MFMA of
// ksg) -> +SBsum -> relu -> out (K=256 via LDS) -> relu -> end -> shift ->
// f32 store. Wave w owns M-tiles w*4..w*4+3.
// ---------------------------------------------------------------------------
__global__ __launch_bounds__(256) void kfinal(
    const ushort_t* __restrict__ actsb,
    const ushort_t* __restrict__ SWf, const ushort_t* __restrict__ OWf,
    const ushort_t* __restrict__ EWf, const float* __restrict__ SBsum,
    float* __restrict__ dout) {
  __shared__ ushort_t M3[64 * M3STR];  // 33 KB mid buffer [t][ch]
  int b = blockIdx.y;
  int t0 = blockIdx.x * 64;
  int lane = threadIdx.x & 63;
  int w = threadIdx.x >> 6;
  int tl = lane & 15, quad = lane >> 4;

  // ---- skip GEMM, K = 16 layers * 64 ch, pipelined acts loads ----
  v4f acc[4][4];
  #pragma unroll
  for (int mt = 0; mt < 4; mt++) {
    int o = (w * 4 + mt) * 16 + quad * 4;
    #pragma unroll
    for (int nt = 0; nt < 4; nt++) {
      v4f z;
      #pragma unroll
      for (int r = 0; r < 4; r++) z[r] = SBsum[o + r];
      acc[mt][nt] = z;
    }
  }
  const ushort_t* abase = actsb + ((size_t)b * TT + t0) * 64;
  const size_t lstr = (size_t)BB * TT * 64;
  v8s bfb[2][4];
  #pragma unroll
  for (int nt = 0; nt < 4; nt++)
    bfb[0][nt] = *(const v8s*)(abase + (nt * 16 + tl) * 64 + quad * 8);
  #pragma unroll 2
  for (int ksg = 0; ksg < 32; ksg++) {
    int cur = ksg & 1;
    if (ksg < 31) {
      int nl = (ksg + 1) >> 1, nk = (ksg + 1) & 1;
      const ushort_t* al = abase + lstr * nl;
      #pragma unroll
      for (int nt = 0; nt < 4; nt++)
        bfb[cur ^ 1][nt] = *(const v8s*)(al + (nt * 16 + tl) * 64 + nk * 32 + quad * 8);
    }
    #pragma unroll
    for (int mt = 0; mt < 4; mt++) {
      v8s a = *(const v8s*)(SWf + (((size_t)(w * 4 + mt) * 32 + ksg) * 64 + lane) * 8);
      #pragma unroll
      for (int nt = 0; nt < 4; nt++)
        acc[mt][nt] = MFMA16(a, bfb[cur][nt], acc[mt][nt], 0, 0, 0);
    }
  }
  #pragma unroll
  for (int mt = 0; mt < 4; mt++) {
    int o = (w * 4 + mt) * 16 + quad * 4;
    #pragma unroll
    for (int nt = 0; nt < 4; nt++) {
      int t = nt * 16 + tl;
      #pragma unroll
      for (int r = 0; r < 4; r++)
        M3[t * M3STR + o + r] = f2bf(fmaxf(acc[mt][nt][r], 0.f));
    }
  }
  __syncthreads();

  // ---- out GEMM, K=256 ----
  v4f acc2[4][4];
  #pragma unroll
  for (int mt = 0; mt < 4; mt++)
    #pragma unroll
    for (int nt = 0; nt < 4; nt++) acc2[mt][nt] = 0.f;
  #pragma unroll
  for (int ks = 0; ks < 8; ks++) {
    v8s bf[4];
    #pragma unroll
    for (int nt = 0; nt < 4; nt++)
      bf[nt] = *(const v8s*)&M3[(nt * 16 + tl) * M3STR + ks * 32 + quad * 8];
    #pragma unroll
    for (int mt = 0; mt < 4; mt++) {
      v8s a = *(const v8s*)(OWf + (((size_t)(w * 4 + mt) * 8 + ks) * 64 + lane) * 8);
      #pragma unroll
      for (int nt = 0; nt < 4; nt++)
        acc2[mt][nt] = MFMA16(a, bf[nt], acc2[mt][nt], 0, 0, 0);
    }
  }
  __syncthreads();   // all M3 reads done before overwrite
  #pragma unroll
  for (int mt = 0; mt < 4; mt++) {
    int o = (w * 4 + mt) * 16 + quad * 4;
    #pragma unroll
    for (int nt = 0; nt < 4; nt++) {
      int t = nt * 16 + tl;
      #pragma unroll
      for (int r = 0; r < 4; r++)
        M3[t * M3STR + o + r] = f2bf(fmaxf(acc2[mt][nt][r], 0.f));
    }
  }
  __syncthreads();

  // ---- end GEMM, K=256, then shifted store ----
  v4f acc3[4][4];
  #pragma unroll
  for (int mt = 0; mt < 4; mt++)
    #pragma unroll
    for (int nt = 0; nt < 4; nt++) acc3[mt][nt] = 0.f;
  #pragma unroll
  for (int ks = 0; ks < 8; ks++) {
    v8s bf[4];
    #pragma unroll
    for (int nt = 0; nt < 4; nt++)
      bf[nt] = *(const v8s*)&M3[(nt * 16 + tl) * M3STR + ks * 32 + quad * 8];
    #pragma unroll
    for (int mt = 0; mt < 4; mt++) {
      v8s a = *(const v8s*)(EWf + (((size_t)(w * 4 + mt) * 8 + ks) * 64 + lane) * 8);
      #pragma unroll
      for (int nt = 0; nt < 4; nt++)
        acc3[mt][nt] = MFMA16(a, bf[nt], acc3[mt][nt], 0, 0, 0);
    }
  }
  #pragma unroll
  for (int mt = 0; mt < 4; mt++) {
    #pragma unroll
    for (int nt = 0; nt < 4; nt++) {
      int tg = t0 + nt * 16 + tl;
      #pragma unroll
      for (int r = 0; r < 4; r++) {
        int o = (w * 4 + mt) * 16 + quad * 4 + r;
        float* ob = dout + ((size_t)b * 256 + o) * TT;
        if (tg == 0) ob[0] = 0.f;
        if (tg + 1 < TT) ob[tg + 1] = acc3[mt][nt][r];
      }
    }
  }
}

// ---------------------------------------------------------------------------
extern "C" void kernel_launch(void* const* d_in, const int* in_sizes, int n_in,
                              void* d_out, int out_size, void* d_ws, size_t ws_size,
                              hipStream_t stream) {
  const float* feat   = (const float*)d_in[0];
  const int*   fin    = (const int*)d_in[1];
  const float* embed  = (const float*)d_in[2];
  const float* up_w   = (const float*)d_in[3];
  const float* up_b   = (const float*)d_in[4];
  const float* cond_w = (const float*)d_in[5];
  const float* cond_b = (const float*)d_in[6];
  const float* dil_w  = (const float*)d_in[7];
  const float* dil_b  = (const float*)d_in[8];
  const float* res_w  = (const float*)d_in[9];
  const float* res_b  = (const float*)d_in[10];
  const float* skip_w = (const float*)d_in[11];
  const float* skip_b = (const float*)d_in[12];
  const float* out_w  = (const float*)d_in[13];
  const float* end_w  = (const float*)d_in[14];

  // Workspace (~175 MB).
  float* ws = (float*)d_ws;
  size_t off = 0;
  float* Bcomb = ws + off; off += NLAYER * 128;
  float* SBsum = ws + off; off += 256;
  ushort_t* ub = (ushort_t*)(ws + off);
  size_t uo = 0;
  ushort_t* A1   = ub + uo; uo += A1SZ;
  ushort_t* A2   = ub + uo; uo += A2SZ;
  ushort_t* SWf  = ub + uo; uo += SWSZ;
  ushort_t* OWf  = ub + uo; uo += OWSZ;
  ushort_t* EWf  = ub + uo; uo += OWSZ;
  ushort_t* Aup  = ub + uo; uo += AUPSZ;
  ushort_t* Bup  = ub + uo; uo += BUPSZ;
  ushort_t* cond = ub + uo; uo += (size_t)BB * TT * 80;
  ushort_t* x0   = ub + uo; uo += (size_t)BB * TT * 64;
  ushort_t* x1   = ub + uo; uo += (size_t)BB * TT * 64;
  ushort_t* acts = ub + uo; uo += (size_t)NLAYER * BB * TT * 64;  // 131 MB

  kprep<<<1024, 256, 0, stream>>>(feat, fin, embed, up_w, cond_w, cond_b,
      dil_w, dil_b, res_w, skip_w, skip_b, out_w, end_w,
      A1, A2, SWf, OWf, EWf, Aup, Bup, x0, Bcomb, SBsum);
  kup<<<250, 256, 0, stream>>>(Aup, Bup, up_b, cond);
  for (int i = 0; i < NLAYER; i++) {
    int d = 1 << (i % 8);
    const ushort_t* xin = (i & 1) ? x1 : x0;
    ushort_t* xout = (i & 1) ? x0 : x1;
    int last = (i == NLAYER - 1) ? 1 : 0;
    klayer<<<dim3(250, BB), 256, 0, stream>>>(xin, xout, cond,
        acts + (size_t)i * BB * TT * 64,
        A1 + (size_t)i * 8 * 7 * 512, A2 + (size_t)i * 4 * 2 * 512,
        Bcomb + i * 128, res_b + (last ? 0 : i) * 64, d, last);
  }
  kfinal<<<dim3(250, BB), 256, 0, stream>>>(acts, SWf, OWf, EWf, SBsum,
      (float*)d_out);
}

// Round 7
// 498.339 us; speedup vs baseline: 6.1617x; 6.1617x over previous
//
#include <hip/hip_runtime.h>
#include <hip/hip_bf16.h>

#define TT 16000
#define BB 4
#define NLAYER 16
#define USTR 232    // klayer stage-1 B-operand row stride (shorts): 224 + 8 pad
#define U2STR 72    // acts row stride (shorts): 64 + 8 pad
#define M3STR 264   // kfinal mid row stride (shorts): 256 + 8 pad
#define ABSTR 72    // kfinal acts-stage row stride (shorts): 64 + 8 pad

#define A1SZ (NLAYER*8*7*512)   // gate-weight A-frags
#define A2SZ (NLAYER*4*2*512)   // res-weight A-frags
#define SWSZ (16*32*512)        // skip-weight A-frags (M=256, K=1024)
#define OWSZ (16*8*512)         // out/end-weight A-frags (M=256, K=256)
#define AUPSZ (20*10*512)       // upsample A-frags (M=320, K=320)
#define BUPSZ (1000*10*512)     // upsample B-frags (K=320, N=16000)

typedef unsigned short ushort_t;
typedef short v8s __attribute__((ext_vector_type(8)));
typedef short v4s __attribute__((ext_vector_type(4)));
typedef float v4f __attribute__((ext_vector_type(4)));

#define MFMA16 __builtin_amdgcn_mfma_f32_16x16x32_bf16

__device__ __forceinline__ float bf2f(ushort_t u) {
  unsigned int x = ((unsigned int)u) << 16;
  float f; __builtin_memcpy(&f, &x, 4); return f;
}
__device__ __forceinline__ ushort_t f2bf(float f) {
  unsigned int x; __builtin_memcpy(&x, &f, 4);
  x += 0x7fffu + ((x >> 16) & 1u);   // RNE
  return (ushort_t)(x >> 16);
}

// ---------------------------------------------------------------------------
// Prep: pack every weight matrix into exact MFMA fragment order (bf16).
// A-frag: elem j of lane l = A[m = mt*16 + (l&15)][k = ks*32 + (l>>4)*8 + j]
// B-frag: elem j of lane l = B[k = ks*32 + (l>>4)*8 + j][n = nt*16 + (l&15)]
// Also: embed gather -> x0, upsample operands Aup/Bup.
// ---------------------------------------------------------------------------
__global__ __launch_bounds__(256) void kprep(
    const float* __restrict__ feat, const int* __restrict__ fin,
    const float* __restrict__ embed, const float* __restrict__ up_w,
    const float* __restrict__ cond_w, const float* __restrict__ cond_b,
    const float* __restrict__ dil_w, const float* __restrict__ dil_b,
    const float* __restrict__ res_w, const float* __restrict__ skip_w,
    const float* __restrict__ skip_b, const float* __restrict__ out_w,
    const float* __restrict__ end_w,
    ushort_t* __restrict__ A1, ushort_t* __restrict__ A2,
    ushort_t* __restrict__ SWf, ushort_t* __restrict__ OWf,
    ushort_t* __restrict__ EWf, ushort_t* __restrict__ Aup,
    ushort_t* __restrict__ Bup, ushort_t* __restrict__ x0,
    float* __restrict__ Bcomb, float* __restrict__ SBsum) {
  int tid = blockIdx.x * 256 + threadIdx.x;
  int np = gridDim.x * 256;
  // A1: gate GEMM [16 layers][8 Mtiles][7 Ksteps][64 lanes][8]
  // K rows: 0..63 = xc (tap1), 64..127 = xp (tap0), 128..207 = cond, pad=0
  for (int idx = tid; idx < A1SZ; idx += np) {
    int j = idx & 7, lane = (idx >> 3) & 63;
    int r_ = idx >> 9;
    int ks = r_ % 7; int r2 = r_ / 7;
    int mt = r2 & 7; int i = r2 >> 3;
    int m = mt * 16 + (lane & 15);
    int k = ks * 32 + (lane >> 4) * 8 + j;
    float v = 0.f;
    if (k < 64)       v = dil_w[((i * 128 + m) * 64 + k) * 2 + 1];
    else if (k < 128) v = dil_w[((i * 128 + m) * 64 + (k - 64)) * 2 + 0];
    else if (k < 208) v = cond_w[(i * 128 + m) * 80 + (k - 128)];
    A1[idx] = f2bf(v);
  }
  // A2: res GEMM [16][4 Mtiles][2 Ksteps][64][8] (layer 15 zeroed/unused)
  for (int idx = tid; idx < A2SZ; idx += np) {
    int j = idx & 7, lane = (idx >> 3) & 63;
    int r_ = idx >> 9;
    int ks = r_ & 1; int mt = (r_ >> 1) & 3; int i = r_ >> 3;
    int m = mt * 16 + (lane & 15);
    int k = ks * 32 + (lane >> 4) * 8 + j;
    A2[idx] = f2bf(i < 15 ? res_w[(i * 64 + m) * 64 + k] : 0.f);
  }
  // SWf: skip GEMM [16 Mtiles][32 Ksteps][64][8], K = layer*64 + ch
  for (int idx = tid; idx < SWSZ; idx += np) {
    int j = idx & 7, lane = (idx >> 3) & 63;
    int r_ = idx >> 9;
    int ks = r_ & 31; int mt = r_ >> 5;
    int m = mt * 16 + (lane & 15);
    int k = ks * 32 + (lane >> 4) * 8 + j;
    int i = k >> 6, ch = k & 63;
    SWf[idx] = f2bf(skip_w[(i * 256 + m) * 64 + ch]);
  }
  // OWf/EWf: [16 Mtiles][8 Ksteps][64][8]
  for (int idx = tid; idx < OWSZ; idx += np) {
    int j = idx & 7, lane = (idx >> 3) & 63;
    int r_ = idx >> 9;
    int ks = r_ & 7; int mt = r_ >> 3;
    int m = mt * 16 + (lane & 15);
    int k = ks * 32 + (lane >> 4) * 8 + j;
    OWf[idx] = f2bf(out_w[m * 256 + k]);
    EWf[idx] = f2bf(end_w[m * 256 + k]);
  }
  // Aup: [20 Mtiles][10 Ks][64][8]; A[mrow=(b*80+q)][km=(m*80+i)] =
  //   feat[b,i,q-m] (0 if q<m)
  for (int idx = tid; idx < AUPSZ; idx += np) {
    int j = idx & 7, lane = (idx >> 3) & 63;
    int r_ = idx >> 9;
    int ks = r_ % 10; int mt = r_ / 10;
    int mrow = mt * 16 + (lane & 15);
    int km = ks * 32 + (lane >> 4) * 8 + j;
    int b = mrow / 80, q = mrow % 80;
    int m = km / 80, i = km % 80;
    int jj = q - m;
    Aup[idx] = f2bf(jj >= 0 ? feat[(b * 80 + i) * 80 + jj] : 0.f);
  }
  // Bup: [1000 Ntiles][10 Ks][64][8]; B[km][col=(o*200+r)] =
  //   up_w[i, o, 200m + r]
  for (int idx = tid; idx < BUPSZ; idx += np) {
    int j = idx & 7, lane = (idx >> 3) & 63;
    int r_ = idx >> 9;
    int ks = r_ % 10; int nt = r_ / 10;
    int km = ks * 32 + (lane >> 4) * 8 + j;
    int m = km / 80, i = km % 80;
    int col = nt * 16 + (lane & 15);
    int o = col / 200, r = col % 200;
    Bup[idx] = f2bf(up_w[(size_t)(i * 80 + o) * 800 + m * 200 + r]);
  }
  // embed gather: x0[b][t][ch] bf16
  for (int idx = tid; idx < BB * TT * 64; idx += np) {
    int k = idx & 63;
    int bt = idx >> 6;            // b*TT + t
    x0[idx] = f2bf(embed[fin[bt] * 64 + k]);
  }
  for (int idx = tid; idx < NLAYER * 128; idx += np)
    Bcomb[idx] = dil_b[idx] + cond_b[idx];
  for (int idx = tid; idx < 256; idx += np) {
    float s = 0.f;
    for (int i = 0; i < NLAYER; i++) s += skip_b[i * 256 + idx];
    SBsum[idx] = s;
  }
}

// ---------------------------------------------------------------------------
// Upsample GEMM, MFMA: M=320 (b,q), K=320 (m,i), N=16000 (o*200+r).
// Pure register GEMM (no LDS): block = 4 N-tiles (64 cols), wave w owns
// M-tiles w*5..w*5+4. Output cond[b][t][80] bf16, t = q*200+r.
// ---------------------------------------------------------------------------
__global__ __launch_bounds__(256) void kup(
    const ushort_t* __restrict__ Aup, const ushort_t* __restrict__ Bup,
    const float* __restrict__ up_b, ushort_t* __restrict__ cond) {
  int nt0 = blockIdx.x * 4;
  int lane = threadIdx.x & 63;
  int w = threadIdx.x >> 6;
  int tl = lane & 15, quad = lane >> 4;
  v4f acc[5][4];
  #pragma unroll
  for (int mt = 0; mt < 5; mt++)
    #pragma unroll
    for (int nt = 0; nt < 4; nt++) acc[mt][nt] = 0.f;
  #pragma unroll
  for (int ks = 0; ks < 10; ks++) {
    v8s bf[4];
    #pragma unroll
    for (int nt = 0; nt < 4; nt++)
      bf[nt] = *(const v8s*)(Bup + (((size_t)(nt0 + nt) * 10 + ks) * 64 + lane) * 8);
    #pragma unroll
    for (int mt = 0; mt < 5; mt++) {
      v8s a = *(const v8s*)(Aup + (((size_t)(w * 5 + mt) * 10 + ks) * 64 + lane) * 8);
      #pragma unroll
      for (int nt = 0; nt < 4; nt++)
        acc[mt][nt] = MFMA16(a, bf[nt], acc[mt][nt], 0, 0, 0);
    }
  }
  #pragma unroll
  for (int mt = 0; mt < 5; mt++) {
    #pragma unroll
    for (int nt = 0; nt < 4; nt++) {
      int col = (nt0 + nt) * 16 + tl;
      int o = col / 200, r = col % 200;
      float bias = up_b[o];
      #pragma unroll
      for (int rg = 0; rg < 4; rg++) {
        int mrow = (w * 5 + mt) * 16 + quad * 4 + rg;
        int b = mrow / 80, q = mrow % 80;
        cond[((size_t)b * TT + q * 200 + r) * 80 + o] = f2bf(acc[mt][nt][rg] + bias);
      }
    }
  }
}

// ---------------------------------------------------------------------------
// One WaveNet layer, MFMA. Block = (64 t) x (one b). 4 waves.
// Stage 1: gate GEMM M=128, K=224 (xc|xp|cond|pad), N=64. Wave w owns
// M-tiles {w, w+4} so channel p and p+64 land in the same lane/reg ->
// lane-local tanh*sigmoid. Acts -> LDS U2 (B-layout) + global (bf16,
// deferred skip). Stage 2: res GEMM M=64 K=64 + residual -> x ping-pong.
// ---------------------------------------------------------------------------
__global__ __launch_bounds__(256) void klayer(
    const ushort_t* __restrict__ xin, ushort_t* __restrict__ xout,
    const ushort_t* __restrict__ cond, ushort_t* __restrict__ actsl,
    const ushort_t* __restrict__ A1l, const ushort_t* __restrict__ A2l,
    const float* __restrict__ Bb, const float* __restrict__ rbias,
    int d, int last) {
  __shared__ ushort_t U[64 * USTR];    // 29.0 KB: B-operand [t][k]
  __shared__ ushort_t U2[64 * U2STR];  //  9.0 KB: acts [t][ch]
  int b = blockIdx.y;
  int t0 = blockIdx.x * 64;
  int tidx = threadIdx.x;
  int lane = tidx & 63;
  int w = tidx >> 6;
  int tl = lane & 15, quad = lane >> 4;

  // ---- stage B-operand: U[t][0..63]=xc, [64..127]=xp, [128..207]=cond ----
  const ushort_t* xb = xin + ((size_t)b * TT + t0) * 64;
  for (int e = tidx * 8; e < 4096; e += 2048) {
    int t = e >> 6, c = e & 63;
    *(v8s*)&U[t * USTR + c] = *(const v8s*)(xb + e);
  }
  for (int e = tidx * 8; e < 4096; e += 2048) {
    int t = e >> 6, c = e & 63;
    int tp = t0 + t - d;
    v8s v = 0;
    if (tp >= 0) v = *(const v8s*)(xin + ((size_t)b * TT + tp) * 64 + c);
    *(v8s*)&U[t * USTR + 64 + c] = v;
  }
  const ushort_t* cbp = cond + ((size_t)b * TT + t0) * 80;
  for (int e = tidx * 8; e < 5120; e += 2048) {
    int t = e / 80, c = e - t * 80;
    *(v8s*)&U[t * USTR + 128 + c] = *(const v8s*)(cbp + e);
  }
  {  // zero K-pad 208..223 (must be finite: mfma multiplies it)
    int e = tidx * 4;
    int t = e >> 4, c = e & 15;
    *(v4s*)&U[t * USTR + 208 + c] = (v4s)0;
  }
  __syncthreads();

  // ---- stage 1: gate GEMM ----
  v4f acc0[4], acc1[4];
  #pragma unroll
  for (int nt = 0; nt < 4; nt++) { acc0[nt] = 0.f; acc1[nt] = 0.f; }
  #pragma unroll
  for (int ks = 0; ks < 7; ks++) {
    v8s a0 = *(const v8s*)(A1l + (((size_t)w * 7 + ks) * 64 + lane) * 8);
    v8s a1 = *(const v8s*)(A1l + (((size_t)(w + 4) * 7 + ks) * 64 + lane) * 8);
    #pragma unroll
    for (int nt = 0; nt < 4; nt++) {
      v8s bf = *(const v8s*)&U[(nt * 16 + tl) * USTR + ks * 32 + quad * 8];
      acc0[nt] = MFMA16(a0, bf, acc0[nt], 0, 0, 0);
      acc1[nt] = MFMA16(a1, bf, acc1[nt], 0, 0, 0);
    }
  }

  // ---- gates: ch = w*16 + quad*4 + r (pair ch, ch+64 lane-local) ----
  int cha = w * 16 + quad * 4;
  float ba[4], bb_[4];
  #pragma unroll
  for (int r = 0; r < 4; r++) { ba[r] = Bb[cha + r]; bb_[r] = Bb[64 + cha + r]; }
  #pragma unroll
  for (int nt = 0; nt < 4; nt++) {
    int t = nt * 16 + tl;
    #pragma unroll
    for (int r = 0; r < 4; r++) {
      float ia = acc0[nt][r] + ba[r];
      float ib = acc1[nt][r] + bb_[r];
      float ax = fabsf(ia);
      float e2 = __expf(-2.f * ax);
      float th = __builtin_copysignf((1.f - e2) / (1.f + e2), ia);
      float sg = 1.f / (1.f + __expf(-ib));
      U2[t * U2STR + cha + r] = f2bf(th * sg);
    }
  }
  __syncthreads();

  // ---- acts -> global (vectorized, deferred skip GEMM reads these) ----
  ushort_t* ab = actsl + ((size_t)b * TT + t0) * 64;
  for (int e = tidx * 8; e < 4096; e += 2048) {
    int t = e >> 6, c = e & 63;
    *(v8s*)(ab + e) = *(const v8s*)&U2[t * U2STR + c];
  }

  // ---- stage 2: res GEMM + residual (dead code at layer 15) ----
  if (!last) {
    v4f acc2[4];
    #pragma unroll
    for (int nt = 0; nt < 4; nt++) {
      v4f z;
      #pragma unroll
      for (int r = 0; r < 4; r++) z[r] = rbias[cha + r];
      acc2[nt] = z;
    }
    #pragma unroll
    for (int ks = 0; ks < 2; ks++) {
      v8s a = *(const v8s*)(A2l + (((size_t)w * 2 + ks) * 64 + lane) * 8);
      #pragma unroll
      for (int nt = 0; nt < 4; nt++) {
        v8s bf = *(const v8s*)&U2[(nt * 16 + tl) * U2STR + ks * 32 + quad * 8];
        acc2[nt] = MFMA16(a, bf, acc2[nt], 0, 0, 0);
      }
    }
    // residual add (xc from U k<64), park in U xp-region for vector store
    #pragma unroll
    for (int nt = 0; nt < 4; nt++) {
      int t = nt * 16 + tl;
      #pragma unroll
      for (int r = 0; r < 4; r++) {
        float xcv = bf2f(U[t * USTR + cha + r]);
        U[t * USTR + 64 + cha + r] = f2bf(acc2[nt][r] + xcv);
      }
    }
    __syncthreads();
    ushort_t* xob = xout + ((size_t)b * TT + t0) * 64;
    for (int e = tidx * 8; e < 4096; e += 2048) {
      int t = e >> 6, c = e & 63;
      *(v8s*)(xob + e) = *(const v8s*)&U[t * USTR + 64 + c];
    }
  }
}

// ---------------------------------------------------------------------------
// Final fused MFMA chain. Skip GEMM (M=256, K=1024): acts tiles staged
// through double-buffered LDS (dedups the 4 waves' identical B-frag loads;
// ds_read latency instead of HBM/L3), prefetch of layer l+1 into NAMED
// registers (q0/q1 — no arrays, nothing spillable) issued before layer l's
// MFMAs, stored to the other LDS buffer after them; ONE barrier per layer.
// Then +SBsum -> relu -> out (K=256) -> relu -> end -> shift -> f32 store.
// The acts stage buffers alias the M3 region: LDS stays 33 KB -> 4 blk/CU.
// ---------------------------------------------------------------------------
__global__ __launch_bounds__(256) void kfinal(
    const ushort_t* __restrict__ actsb,
    const ushort_t* __restrict__ SWf, const ushort_t* __restrict__ OWf,
    const ushort_t* __restrict__ EWf, const float* __restrict__ SBsum,
    float* __restrict__ dout) {
  __shared__ ushort_t SMEM[64 * M3STR];   // 33 KB; skip-phase: AB dbuf, then M3
  int b = blockIdx.y;
  int t0 = blockIdx.x * 64;
  int tidx = threadIdx.x;
  int lane = tidx & 63;
  int w = tidx >> 6;
  int tl = lane & 15, quad = lane >> 4;

  // ---- skip GEMM, K = 16 layers * 64 ch ----
  v4f acc[4][4];
  #pragma unroll
  for (int mt = 0; mt < 4; mt++) {
    int o = (w * 4 + mt) * 16 + quad * 4;
    #pragma unroll
    for (int nt = 0; nt < 4; nt++) {
      v4f z;
      #pragma unroll
      for (int r = 0; r < 4; r++) z[r] = SBsum[o + r];
      acc[mt][nt] = z;
    }
  }
  const ushort_t* abase = actsb + ((size_t)b * TT + t0) * 64;
  const size_t lstr = (size_t)BB * TT * 64;
  int tq = tidx >> 2;               // t-row this thread copies (0..63)
  int pq = (tidx & 3) * 16;         // 16-short chunk within the row
  {  // preload layer 0 -> buffer 0
    const ushort_t* a0 = abase + tq * 64 + pq;
    v8s p0 = *(const v8s*)(a0);
    v8s p1 = *(const v8s*)(a0 + 8);
    *(v8s*)&SMEM[tq * ABSTR + pq] = p0;
    *(v8s*)&SMEM[tq * ABSTR + pq + 8] = p1;
  }
  __syncthreads();
  for (int l = 0; l < NLAYER; l++) {
    // prefetch next layer's tile into named regs (branchless: clamp index)
    int ln = (l + 1 < NLAYER) ? (l + 1) : (NLAYER - 1);
    const ushort_t* an = abase + (size_t)ln * lstr + tq * 64 + pq;
    v8s q0 = *(const v8s*)(an);
    v8s q1 = *(const v8s*)(an + 8);
    // compute layer l from LDS buffer l&1
    const ushort_t* ABc = SMEM + (l & 1) * (64 * ABSTR);
    #pragma unroll
    for (int ks2 = 0; ks2 < 2; ks2++) {
      int ksg = l * 2 + ks2;
      v8s bf[4];
      #pragma unroll
      for (int nt = 0; nt < 4; nt++)
        bf[nt] = *(const v8s*)&ABc[(nt * 16 + tl) * ABSTR + ks2 * 32 + quad * 8];
      #pragma unroll
      for (int mt = 0; mt < 4; mt++) {
        v8s a = *(const v8s*)(SWf + (((size_t)(w * 4 + mt) * 32 + ksg) * 64 + lane) * 8);
        #pragma unroll
        for (int nt = 0; nt < 4; nt++)
          acc[mt][nt] = MFMA16(a, bf[nt], acc[mt][nt], 0, 0, 0);
      }
    }
    // store prefetched tile into the other buffer (dead store at l=15)
    ushort_t* ABn = SMEM + ((l + 1) & 1) * (64 * ABSTR);
    *(v8s*)&ABn[tq * ABSTR + pq] = q0;
    *(v8s*)&ABn[tq * ABSTR + pq + 8] = q1;
    __syncthreads();
  }
  // ---- SMEM now reused as M3 [t][256+8] ----
  #pragma unroll
  for (int mt = 0; mt < 4; mt++) {
    int o = (w * 4 + mt) * 16 + quad * 4;
    #pragma unroll
    for (int nt = 0; nt < 4; nt++) {
      int t = nt * 16 + tl;
      #pragma unroll
      for (int r = 0; r < 4; r++)
        SMEM[t * M3STR + o + r] = f2bf(fmaxf(acc[mt][nt][r], 0.f));
    }
  }
  __syncthreads();

  // ---- out GEMM, K=256 ----
  v4f acc2[4][4];
  #pragma unroll
  for (int mt = 0; mt < 4; mt++)
    #pragma unroll
    for (int nt = 0; nt < 4; nt++) acc2[mt][nt] = 0.f;
  #pragma unroll
  for (int ks = 0; ks < 8; ks++) {
    v8s bf[4];
    #pragma unroll
    for (int nt = 0; nt < 4; nt++)
      bf[nt] = *(const v8s*)&SMEM[(nt * 16 + tl) * M3STR + ks * 32 + quad * 8];
    #pragma unroll
    for (int mt = 0; mt < 4; mt++) {
      v8s a = *(const v8s*)(OWf + (((size_t)(w * 4 + mt) * 8 + ks) * 64 + lane) * 8);
      #pragma unroll
      for (int nt = 0; nt < 4; nt++)
        acc2[mt][nt] = MFMA16(a, bf[nt], acc2[mt][nt], 0, 0, 0);
    }
  }
  __syncthreads();   // all M3 reads done before overwrite
  #pragma unroll
  for (int mt = 0; mt < 4; mt++) {
    int o = (w * 4 + mt) * 16 + quad * 4;
    #pragma unroll
    for (int nt = 0; nt < 4; nt++) {
      int t = nt * 16 + tl;
      #pragma unroll
      for (int r = 0; r < 4; r++)
        SMEM[t * M3STR + o + r] = f2bf(fmaxf(acc2[mt][nt][r], 0.f));
    }
  }
  __syncthreads();

  // ---- end GEMM, K=256, then shifted store ----
  v4f acc3[4][4];
  #pragma unroll
  for (int mt = 0; mt < 4; mt++)
    #pragma unroll
    for (int nt = 0; nt < 4; nt++) acc3[mt][nt] = 0.f;
  #pragma unroll
  for (int ks = 0; ks < 8; ks++) {
    v8s bf[4];
    #pragma unroll
    for (int nt = 0; nt < 4; nt++)
      bf[nt] = *(const v8s*)&SMEM[(nt * 16 + tl) * M3STR + ks * 32 + quad * 8];
    #pragma unroll
    for (int mt = 0; mt < 4; mt++) {
      v8s a = *(const v8s*)(EWf + (((size_t)(w * 4 + mt) * 8 + ks) * 64 + lane) * 8);
      #pragma unroll
      for (int nt = 0; nt < 4; nt++)
        acc3[mt][nt] = MFMA16(a, bf[nt], acc3[mt][nt], 0, 0, 0);
    }
  }
  #pragma unroll
  for (int mt = 0; mt < 4; mt++) {
    #pragma unroll
    for (int nt = 0; nt < 4; nt++) {
      int tg = t0 + nt * 16 + tl;
      #pragma unroll
      for (int r = 0; r < 4; r++) {
        int o = (w * 4 + mt) * 16 + quad * 4 + r;
        float* ob = dout + ((size_t)b * 256 + o) * TT;
        if (tg == 0) ob[0] = 0.f;
        if (tg + 1 < TT) ob[tg + 1] = acc3[mt][nt][r];
      }
    }
  }
}

// ---------------------------------------------------------------------------
extern "C" void kernel_launch(void* const* d_in, const int* in_sizes, int n_in,
                              void* d_out, int out_size, void* d_ws, size_t ws_size,
                              hipStream_t stream) {
  const float* feat   = (const float*)d_in[0];
  const int*   fin    = (const int*)d_in[1];
  const float* embed  = (const float*)d_in[2];
  const float* up_w   = (const float*)d_in[3];
  const float* up_b   = (const float*)d_in[4];
  const float* cond_w = (const float*)d_in[5];
  const float* cond_b = (const float*)d_in[6];
  const float* dil_w  = (const float*)d_in[7];
  const float* dil_b  = (const float*)d_in[8];
  const float* res_w  = (const float*)d_in[9];
  const float* res_b  = (const float*)d_in[10];
  const float* skip_w = (const float*)d_in[11];
  const float* skip_b = (const float*)d_in[12];
  const float* out_w  = (const float*)d_in[13];
  const float* end_w  = (const float*)d_in[14];

  // Workspace (~175 MB).
  float* ws = (float*)d_ws;
  size_t off = 0;
  float* Bcomb = ws + off; off += NLAYER * 128;
  float* SBsum = ws + off; off += 256;
  ushort_t* ub = (ushort_t*)(ws + off);
  size_t uo = 0;
  ushort_t* A1   = ub + uo; uo += A1SZ;
  ushort_t* A2   = ub + uo; uo += A2SZ;
  ushort_t* SWf  = ub + uo; uo += SWSZ;
  ushort_t* OWf  = ub + uo; uo += OWSZ;
  ushort_t* EWf  = ub + uo; uo += OWSZ;
  ushort_t* Aup  = ub + uo; uo += AUPSZ;
  ushort_t* Bup  = ub + uo; uo += BUPSZ;
  ushort_t* cond = ub + uo; uo += (size_t)BB * TT * 80;
  ushort_t* x0   = ub + uo; uo += (size_t)BB * TT * 64;
  ushort_t* x1   = ub + uo; uo += (size_t)BB * TT * 64;
  ushort_t* acts = ub + uo; uo += (size_t)NLAYER * BB * TT * 64;  // 131 MB

  kprep<<<1024, 256, 0, stream>>>(feat, fin, embed, up_w, cond_w, cond_b,
      dil_w, dil_b, res_w, skip_w, skip_b, out_w, end_w,
      A1, A2, SWf, OWf, EWf, Aup, Bup, x0, Bcomb, SBsum);
  kup<<<250, 256, 0, stream>>>(Aup, Bup, up_b, cond);
  for (int i = 0; i < NLAYER; i++) {
    int d = 1 << (i % 8);
    const ushort_t* xin = (i & 1) ? x1 : x0;
    ushort_t* xout = (i & 1) ? x0 : x1;
    int last = (i == NLAYER - 1) ? 1 : 0;
    klayer<<<dim3(250, BB), 256, 0, stream>>>(xin, xout, cond,
        acts + (size_t)i * BB * TT * 64,
        A1 + (size_t)i * 8 * 7 * 512, A2 + (size_t)i * 4 * 2 * 512,
        Bcomb + i * 128, res_b + (last ? 0 : i) * 64, d, last);
  }
  kfinal<<<dim3(250, BB), 256, 0, stream>>>(acts, SWf, OWf, EWf, SBsum,
      (float*)d_out);
}